// Round 16
// baseline (108.337 us; speedup 1.0000x reference)
//
#include <hip/hip_runtime.h>
#include <math.h>

using short8   = __attribute__((ext_vector_type(8))) short;
using floatx4  = __attribute__((ext_vector_type(4))) float;
using ushort4v = __attribute__((ext_vector_type(4))) unsigned short;

__device__ __forceinline__ unsigned short f2bf(float x) {
  union { float f; unsigned u; } v; v.f = x;
  unsigned r = (v.u + 0x7FFFu + ((v.u >> 16) & 1u)) >> 16;
  return (unsigned short)r;
}
__device__ __forceinline__ float bf2f(unsigned short u) {
  union { unsigned u; float f; } v; v.u = ((unsigned)u) << 16;
  return v.f;
}
__device__ __forceinline__ short8 cvt8(const float* p) {
  float4 v0 = *(const float4*)p;
  float4 v1 = *(const float4*)(p + 4);
  short8 r;
  r[0] = (short)f2bf(v0.x); r[1] = (short)f2bf(v0.y);
  r[2] = (short)f2bf(v0.z); r[3] = (short)f2bf(v0.w);
  r[4] = (short)f2bf(v1.x); r[5] = (short)f2bf(v1.y);
  r[6] = (short)f2bf(v1.z); r[7] = (short)f2bf(v1.w);
  return r;
}

// ---------------- K0a: pack adj int32 -> bit per element (coalesced) ----------------
__global__ __launch_bounds__(256) void adj_pack(
    const int* __restrict__ adj, unsigned* __restrict__ pk) {
  size_t tid = (size_t)blockIdx.x * 256 + threadIdx.x;   // 0..1,048,575
  const int* src = adj + tid * 32;
  unsigned r = 0;
#pragma unroll
  for (int q = 0; q < 8; ++q) {
    int4 v = *(const int4*)(src + q * 4);
    r |= ((unsigned)v.x << (4 * q)) | ((unsigned)v.y << (4 * q + 1)) |
         ((unsigned)v.z << (4 * q + 2)) | ((unsigned)v.w << (4 * q + 3));
  }
  pk[tid] = r;
}

// ---------------- K0b: W (f32 [k][n]) -> Wt bf16 tile layout ----------------
__global__ __launch_bounds__(256) void wt_conv(
    const float* __restrict__ W, unsigned short* __restrict__ Wt) {
  int c = blockIdx.x;
  int k = threadIdx.x;
  int kt = k >> 5;
  Wt[(size_t)(kt * 256 + c) * 32 + (k & 31)] = f2bf(W[(size_t)k * 256 + c]);
}

// ---------------- K1: Wh = h @ W via bf16 MFMA (f32 accum) + fused g-dot ----------------
__global__ __launch_bounds__(256) void wh_mfma(
    const float* __restrict__ h, const unsigned short* __restrict__ Wt,
    unsigned short* __restrict__ Whb, const float* __restrict__ a,
    float* __restrict__ g) {
  const int m0 = blockIdx.x * 32;
  const int t  = threadIdx.x;
  const int w  = t >> 6, L = t & 63;
  const int fr = L & 15, kc = L >> 4;

  const float* hrow0 = h + (size_t)(m0 + fr) * 256;
  const float* hrow1 = h + (size_t)(m0 + 16 + fr) * 256;

  floatx4 acc[2][4];
#pragma unroll
  for (int i = 0; i < 2; ++i)
#pragma unroll
    for (int n = 0; n < 4; ++n) acc[i][n] = (floatx4)0.0f;

#pragma unroll
  for (int kt = 0; kt < 8; ++kt) {
    short8 a0 = cvt8(hrow0 + kt * 32 + kc * 8);
    short8 a1 = cvt8(hrow1 + kt * 32 + kc * 8);
#pragma unroll
    for (int nf = 0; nf < 4; ++nf) {
      int c = w * 64 + nf * 16 + fr;
      short8 bf = *(const short8*)(Wt + (size_t)(kt * 256 + c) * 32 + kc * 8);
      acc[0][nf] = __builtin_amdgcn_mfma_f32_16x16x32_bf16(a0, bf, acc[0][nf], 0, 0, 0);
      acc[1][nf] = __builtin_amdgcn_mfma_f32_16x16x32_bf16(a1, bf, acc[1][nf], 0, 0, 0);
    }
  }

  const int q = L >> 4;
  float a2v[4];
#pragma unroll
  for (int nf = 0; nf < 4; ++nf) a2v[nf] = a[256 + w * 64 + nf * 16 + fr];
#pragma unroll
  for (int mf = 0; mf < 2; ++mf) {
    float p[4] = {0.f, 0.f, 0.f, 0.f};
#pragma unroll
    for (int nf = 0; nf < 4; ++nf) {
#pragma unroll
      for (int jj = 0; jj < 4; ++jj) {
        int row = m0 + mf * 16 + q * 4 + jj;
        Whb[(size_t)row * 256 + w * 64 + nf * 16 + fr] = f2bf(acc[mf][nf][jj]);
        p[jj] += acc[mf][nf][jj] * a2v[nf];
      }
    }
#pragma unroll
    for (int jj = 0; jj < 4; ++jj) {
#pragma unroll
      for (int off = 1; off < 16; off <<= 1) p[jj] += __shfl_xor(p[jj], off);
      if (fr == 0) atomicAdd(&g[m0 + mf * 16 + q * 4 + jj], p[jj]);
    }
  }
}

// ---------------- K2b: per-batch max of g ----------------
__global__ __launch_bounds__(256) void batch_max(
    const float* __restrict__ g, float* __restrict__ Mb) {
  __shared__ float red[4];
  int b = blockIdx.x, t = threadIdx.x;
  float m = -1e30f;
  for (int i = t; i < 2048; i += 256) m = fmaxf(m, g[(size_t)b * 2048 + i]);
#pragma unroll
  for (int off = 32; off > 0; off >>= 1) m = fmaxf(m, __shfl_xor(m, off));
  if ((t & 63) == 0) red[t >> 6] = m;
  __syncthreads();
  if (t == 0) Mb[b] = fmaxf(fmaxf(red[0], red[1]), fmaxf(red[2], red[3]));
}

// ---------------- K2c: tile-contiguous B (72-short padded rows) ----------------
__global__ __launch_bounds__(256) void build_bt(
    const unsigned short* __restrict__ Whb, const float* __restrict__ g,
    const float* __restrict__ Mb, unsigned short* __restrict__ Bt) {
  __shared__ __align__(16) unsigned short tile[320 * 72];
  const int blk = blockIdx.x;
  const int b   = blk >> 5;
  const int j0  = (blk & 31) * 64;
  const int kt_base = (blk & 31) * 2;
  const int t   = threadIdx.x;
  const int j   = t & 63;
  const int q0  = t >> 6;
  const int row = b * 2048 + j0 + j;
  const float s = expf(g[row] - Mb[b]);
  for (int q = q0; q < 64; q += 4) {
    ushort4v wv = *(const ushort4v*)&Whb[(size_t)row * 256 + q * 4];
    int c = q * 4;
    tile[(c + 0) * 72 + j] = f2bf(s * bf2f(wv[0]));
    tile[(c + 1) * 72 + j] = f2bf(s * bf2f(wv[1]));
    tile[(c + 2) * 72 + j] = f2bf(s * bf2f(wv[2]));
    tile[(c + 3) * 72 + j] = f2bf(s * bf2f(wv[3]));
  }
  if (q0 == 0) tile[256 * 72 + j] = f2bf(s);
  for (int z = t; z < 63 * 64; z += 256) {
    int c = 257 + (z >> 6);
    tile[c * 72 + (z & 63)] = 0;
  }
  __syncthreads();
#pragma unroll
  for (int p = 0; p < 10; ++p) {
    int id = t + 256 * p;
    int c = id >> 3, off = id & 7;
    int kt_l = off >> 2, slot = off & 3;
    size_t dst = ((size_t)((b * 64 + kt_base + kt_l) * 320 + c)) * 64 + (slot << 4);
    *(int4*)((char*)Bt + dst) = *(const int4*)&tile[c * 72 + off * 8];
  }
}

// ---------------- K3: [num|den] = adj @ Bt^T ----------------
// BM=128: each wave computes 4 M-frags (rows wm*64 + mf*16 + fr) x 5 N-frags.
// Halves the B issue volume (each 20KB B tile feeds 128 rows, was 64):
// 655 MB -> 328 MB chip-wide. Grid 128 (b=bid&7 XCD-pinned, 16 row-blocks).
// A = packed bits in LDS (coalesced 32KB prologue). B direct global->reg,
// 3 named sets, plain compiler scheduling (no asm, no loop barriers).
__global__ __launch_bounds__(512, 1) void gat_main(
    const unsigned* __restrict__ pk, const unsigned short* __restrict__ Bt,
    float* __restrict__ out) {
  __shared__ __align__(16) char lds[128 * 272 + 512];  // A bits (stride 272) + den
  const int bid = blockIdx.x;
  const int b   = bid & 7;
  const int rb  = bid >> 3;
  const int i0  = rb * 128;
  const int tid = threadIdx.x;
  const int w   = tid >> 6, L = tid & 63;
  const int wm  = w >> 2, wn = w & 3;     // row-group (0-1), col-group (0-3)
  const int fr  = L & 15, kc = L >> 4;

  // prologue: stage 128 rows x 256B of packed bits, row stride 272 (coalesced:
  // the strip is one contiguous 32KB region of pk; each thread copies 64B)
  {
    int r = tid >> 2, seg = tid & 3;
    const char* src = (const char*)pk + ((size_t)(b * 2048 + i0 + r) * 256 + seg * 64);
    char* dst = lds + r * 272 + seg * 64;
    *(int4*)(dst)      = *(const int4*)(src);
    *(int4*)(dst + 16) = *(const int4*)(src + 16);
    *(int4*)(dst + 32) = *(const int4*)(src + 32);
    *(int4*)(dst + 48) = *(const int4*)(src + 48);
  }
  __syncthreads();

  const char* bsrc = (const char*)Bt + (size_t)b * 1310720
                   + (size_t)(wn * 80 + fr) * 64 + (kc << 4);
  const char* arow0 = lds + (wm * 64 + fr) * 272;        // mf=0
  const char* arow1 = arow0 + 16 * 272;                  // mf=1
  const char* arow2 = arow0 + 32 * 272;                  // mf=2
  const char* arow3 = arow0 + 48 * 272;                  // mf=3
  const int   ksh   = kc * 8;

  floatx4 acc[4][5];
#pragma unroll
  for (int i = 0; i < 4; ++i)
#pragma unroll
    for (int n = 0; n < 5; ++n) acc[i][n] = (floatx4)0.0f;

  short8 s0[5], s1[5], s2[5];

#define LOADB(TT, SET) {                                  \
    const char* p_ = bsrc + (size_t)(TT) * 20480;         \
    SET[0] = *(const short8*)(p_);                        \
    SET[1] = *(const short8*)(p_ + 1024);                 \
    SET[2] = *(const short8*)(p_ + 2048);                 \
    SET[3] = *(const short8*)(p_ + 3072);                 \
    SET[4] = *(const short8*)(p_ + 4096);                 \
  }

  // bit->bf16 expand: y = x | x<<15; dword j = ((y>>2j) & 0x10001) * 0x3F80
#define AFRAG(WORD, DST) {                                \
    unsigned x_ = ((WORD) >> ksh) & 0xFFu;                \
    unsigned y_ = x_ | (x_ << 15);                        \
    union { unsigned u[4]; short8 s; } c_;                \
    c_.u[0] = (y_        & 0x10001u) * 0x3F80u;           \
    c_.u[1] = ((y_ >> 2) & 0x10001u) * 0x3F80u;           \
    c_.u[2] = ((y_ >> 4) & 0x10001u) * 0x3F80u;           \
    c_.u[3] = ((y_ >> 6) & 0x10001u) * 0x3F80u;           \
    DST = c_.s;                                           \
  }

#define COMPUTE(TT, SET) {                                                       \
    unsigned w0_ = *(const unsigned*)(arow0 + (TT) * 4);                         \
    unsigned w1_ = *(const unsigned*)(arow1 + (TT) * 4);                         \
    unsigned w2_ = *(const unsigned*)(arow2 + (TT) * 4);                         \
    unsigned w3_ = *(const unsigned*)(arow3 + (TT) * 4);                         \
    short8 af0_, af1_, af2_, af3_;                                               \
    AFRAG(w0_, af0_); AFRAG(w1_, af1_); AFRAG(w2_, af2_); AFRAG(w3_, af3_);      \
    _Pragma("unroll")                                                            \
    for (int nf = 0; nf < 5; ++nf) {                                             \
      acc[0][nf] = __builtin_amdgcn_mfma_f32_16x16x32_bf16(af0_, SET[nf], acc[0][nf], 0, 0, 0); \
      acc[1][nf] = __builtin_amdgcn_mfma_f32_16x16x32_bf16(af1_, SET[nf], acc[1][nf], 0, 0, 0); \
      acc[2][nf] = __builtin_amdgcn_mfma_f32_16x16x32_bf16(af2_, SET[nf], acc[2][nf], 0, 0, 0); \
      acc[3][nf] = __builtin_amdgcn_mfma_f32_16x16x32_bf16(af3_, SET[nf], acc[3][nf], 0, 0, 0); \
    }                                                                            \
  }

  LOADB(0, s0); LOADB(1, s1); LOADB(2, s2);

#pragma unroll 1
  for (int kt = 0; kt < 60; kt += 3) {
    COMPUTE(kt + 0, s0);  LOADB(kt + 3, s0);
    COMPUTE(kt + 1, s1);  LOADB(kt + 4, s1);
    COMPUTE(kt + 2, s2);  LOADB(kt + 5, s2);
  }
  // tail: s0=60, s1=61, s2=62
  COMPUTE(60, s0);  LOADB(63, s0);
  COMPUTE(61, s1);
  COMPUTE(62, s2);
  COMPUTE(63, s0);

  // epilogue: den = col 256 -> wn==3, nf==1, fr==0
  float* denL = (float*)(lds + 128 * 272);
  const int q = L >> 4;
  if (wn == 3 && fr == 0) {
#pragma unroll
    for (int mf = 0; mf < 4; ++mf)
#pragma unroll
      for (int jj = 0; jj < 4; ++jj)
        denL[wm * 64 + mf * 16 + q * 4 + jj] = acc[mf][1][jj];
  }
  __syncthreads();
  float invd[4][4];
#pragma unroll
  for (int mf = 0; mf < 4; ++mf)
#pragma unroll
    for (int jj = 0; jj < 4; ++jj)
      invd[mf][jj] = 1.0f / denL[wm * 64 + mf * 16 + q * 4 + jj];
#pragma unroll
  for (int mf = 0; mf < 4; ++mf) {
#pragma unroll
    for (int nf = 0; nf < 5; ++nf) {
      int col = wn * 80 + nf * 16 + fr;
      if (col < 256) {
#pragma unroll
        for (int jj = 0; jj < 4; ++jj) {
          int row = wm * 64 + mf * 16 + q * 4 + jj;
          float v = acc[mf][nf][jj] * invd[mf][jj];
          v = (v > 0.0f) ? v : expm1f(v);
          out[((size_t)b * 2048 + i0 + row) * 256 + col] = v;
        }
      }
    }
  }
#undef COMPUTE
#undef AFRAG
#undef LOADB
}

extern "C" void kernel_launch(void* const* d_in, const int* in_sizes, int n_in,
                              void* d_out, int out_size, void* d_ws, size_t ws_size,
                              hipStream_t stream) {
  const float* h   = (const float*)d_in[0];
  const int*   adj = (const int*)d_in[1];
  const float* W   = (const float*)d_in[2];
  const float* a   = (const float*)d_in[3];
  float* out = (float*)d_out;

  char* ws = (char*)d_ws;
  if (ws_size < 23265536) return;
  unsigned short* Whb = (unsigned short*)ws;              //  8,388,608 B
  float* g            = (float*)(ws + 8388608);           //     65,536 B
  float* Mb           = (float*)(ws + 8454144);           //        256 B
  unsigned short* Bt  = (unsigned short*)(ws + 8454400);  // 10,485,760 B
  unsigned short* Wt  = (unsigned short*)(ws + 18940160); //    131,072 B
  unsigned* pk        = (unsigned*)(ws + 19071232);       //  4,194,304 B

  hipMemsetAsync(g, 0, 65536, stream);
  adj_pack <<<4096, 256, 0, stream>>>(adj, pk);
  wt_conv  <<<256,  256, 0, stream>>>(W, Wt);
  wh_mfma  <<<512,  256, 0, stream>>>(h, Wt, Whb, a, g);
  batch_max<<<8,    256, 0, stream>>>(g, Mb);
  build_bt <<<256,  256, 0, stream>>>(Whb, g, Mb, Bt);
  gat_main <<<128,  512, 0, stream>>>(pk, Bt, out);
}

// Round 17
// 103.510 us; speedup vs baseline: 1.0466x; 1.0466x over previous
//
#include <hip/hip_runtime.h>
#include <math.h>

using short8   = __attribute__((ext_vector_type(8))) short;
using floatx4  = __attribute__((ext_vector_type(4))) float;
using ushort4v = __attribute__((ext_vector_type(4))) unsigned short;
using uint4v   = __attribute__((ext_vector_type(4))) unsigned int;

__device__ __forceinline__ unsigned short f2bf(float x) {
  union { float f; unsigned u; } v; v.f = x;
  unsigned r = (v.u + 0x7FFFu + ((v.u >> 16) & 1u)) >> 16;
  return (unsigned short)r;
}
__device__ __forceinline__ float bf2f(unsigned short u) {
  union { unsigned u; float f; } v; v.u = ((unsigned)u) << 16;
  return v.f;
}
__device__ __forceinline__ short8 cvt8(const float* p) {
  float4 v0 = *(const float4*)p;
  float4 v1 = *(const float4*)(p + 4);
  short8 r;
  r[0] = (short)f2bf(v0.x); r[1] = (short)f2bf(v0.y);
  r[2] = (short)f2bf(v0.z); r[3] = (short)f2bf(v0.w);
  r[4] = (short)f2bf(v1.x); r[5] = (short)f2bf(v1.y);
  r[6] = (short)f2bf(v1.z); r[7] = (short)f2bf(v1.w);
  return r;
}
__device__ __forceinline__ short8 bc8(uint4v v) {
  union { uint4v u; short8 s; } x; x.u = v; return x.s;
}

// ---------------- K0a: pack adj int32 -> bit per element (coalesced) ----------------
__global__ __launch_bounds__(256) void adj_pack(
    const int* __restrict__ adj, unsigned* __restrict__ pk) {
  size_t tid = (size_t)blockIdx.x * 256 + threadIdx.x;   // 0..1,048,575
  const int* src = adj + tid * 32;
  unsigned r = 0;
#pragma unroll
  for (int q = 0; q < 8; ++q) {
    int4 v = *(const int4*)(src + q * 4);
    r |= ((unsigned)v.x << (4 * q)) | ((unsigned)v.y << (4 * q + 1)) |
         ((unsigned)v.z << (4 * q + 2)) | ((unsigned)v.w << (4 * q + 3));
  }
  pk[tid] = r;
}

// ---------------- K0b: W (f32 [k][n]) -> Wt bf16 tile layout ----------------
__global__ __launch_bounds__(256) void wt_conv(
    const float* __restrict__ W, unsigned short* __restrict__ Wt) {
  int c = blockIdx.x;
  int k = threadIdx.x;
  int kt = k >> 5;
  Wt[(size_t)(kt * 256 + c) * 32 + (k & 31)] = f2bf(W[(size_t)k * 256 + c]);
}

// ---------------- K1: Wh = h @ W via bf16 MFMA (f32 accum) + fused g-dot ----------------
__global__ __launch_bounds__(256) void wh_mfma(
    const float* __restrict__ h, const unsigned short* __restrict__ Wt,
    unsigned short* __restrict__ Whb, const float* __restrict__ a,
    float* __restrict__ g) {
  const int m0 = blockIdx.x * 32;
  const int t  = threadIdx.x;
  const int w  = t >> 6, L = t & 63;
  const int fr = L & 15, kc = L >> 4;

  const float* hrow0 = h + (size_t)(m0 + fr) * 256;
  const float* hrow1 = h + (size_t)(m0 + 16 + fr) * 256;

  floatx4 acc[2][4];
#pragma unroll
  for (int i = 0; i < 2; ++i)
#pragma unroll
    for (int n = 0; n < 4; ++n) acc[i][n] = (floatx4)0.0f;

#pragma unroll
  for (int kt = 0; kt < 8; ++kt) {
    short8 a0 = cvt8(hrow0 + kt * 32 + kc * 8);
    short8 a1 = cvt8(hrow1 + kt * 32 + kc * 8);
#pragma unroll
    for (int nf = 0; nf < 4; ++nf) {
      int c = w * 64 + nf * 16 + fr;
      short8 bf = *(const short8*)(Wt + (size_t)(kt * 256 + c) * 32 + kc * 8);
      acc[0][nf] = __builtin_amdgcn_mfma_f32_16x16x32_bf16(a0, bf, acc[0][nf], 0, 0, 0);
      acc[1][nf] = __builtin_amdgcn_mfma_f32_16x16x32_bf16(a1, bf, acc[1][nf], 0, 0, 0);
    }
  }

  const int q = L >> 4;
  float a2v[4];
#pragma unroll
  for (int nf = 0; nf < 4; ++nf) a2v[nf] = a[256 + w * 64 + nf * 16 + fr];
#pragma unroll
  for (int mf = 0; mf < 2; ++mf) {
    float p[4] = {0.f, 0.f, 0.f, 0.f};
#pragma unroll
    for (int nf = 0; nf < 4; ++nf) {
#pragma unroll
      for (int jj = 0; jj < 4; ++jj) {
        int row = m0 + mf * 16 + q * 4 + jj;
        Whb[(size_t)row * 256 + w * 64 + nf * 16 + fr] = f2bf(acc[mf][nf][jj]);
        p[jj] += acc[mf][nf][jj] * a2v[nf];
      }
    }
#pragma unroll
    for (int jj = 0; jj < 4; ++jj) {
#pragma unroll
      for (int off = 1; off < 16; off <<= 1) p[jj] += __shfl_xor(p[jj], off);
      if (fr == 0) atomicAdd(&g[m0 + mf * 16 + q * 4 + jj], p[jj]);
    }
  }
}

// ---------------- K2b: per-batch max of g ----------------
__global__ __launch_bounds__(256) void batch_max(
    const float* __restrict__ g, float* __restrict__ Mb) {
  __shared__ float red[4];
  int b = blockIdx.x, t = threadIdx.x;
  float m = -1e30f;
  for (int i = t; i < 2048; i += 256) m = fmaxf(m, g[(size_t)b * 2048 + i]);
#pragma unroll
  for (int off = 32; off > 0; off >>= 1) m = fmaxf(m, __shfl_xor(m, off));
  if ((t & 63) == 0) red[t >> 6] = m;
  __syncthreads();
  if (t == 0) Mb[b] = fmaxf(fmaxf(red[0], red[1]), fmaxf(red[2], red[3]));
}

// ---------------- K2c: tile-contiguous B (72-short padded rows) ----------------
__global__ __launch_bounds__(256) void build_bt(
    const unsigned short* __restrict__ Whb, const float* __restrict__ g,
    const float* __restrict__ Mb, unsigned short* __restrict__ Bt) {
  __shared__ __align__(16) unsigned short tile[320 * 72];
  const int blk = blockIdx.x;
  const int b   = blk >> 5;
  const int j0  = (blk & 31) * 64;
  const int kt_base = (blk & 31) * 2;
  const int t   = threadIdx.x;
  const int j   = t & 63;
  const int q0  = t >> 6;
  const int row = b * 2048 + j0 + j;
  const float s = expf(g[row] - Mb[b]);
  for (int q = q0; q < 64; q += 4) {
    ushort4v wv = *(const ushort4v*)&Whb[(size_t)row * 256 + q * 4];
    int c = q * 4;
    tile[(c + 0) * 72 + j] = f2bf(s * bf2f(wv[0]));
    tile[(c + 1) * 72 + j] = f2bf(s * bf2f(wv[1]));
    tile[(c + 2) * 72 + j] = f2bf(s * bf2f(wv[2]));
    tile[(c + 3) * 72 + j] = f2bf(s * bf2f(wv[3]));
  }
  if (q0 == 0) tile[256 * 72 + j] = f2bf(s);
  for (int z = t; z < 63 * 64; z += 256) {
    int c = 257 + (z >> 6);
    tile[c * 72 + (z & 63)] = 0;
  }
  __syncthreads();
#pragma unroll
  for (int p = 0; p < 10; ++p) {
    int id = t + 256 * p;
    int c = id >> 3, off = id & 7;
    int kt_l = off >> 2, slot = off & 3;
    size_t dst = ((size_t)((b * 64 + kt_base + kt_l) * 320 + c)) * 64 + (slot << 4);
    *(int4*)((char*)Bt + dst) = *(const int4*)&tile[c * 72 + off * 8];
  }
}

// ---------------- K3: [num|den] = adj @ Bt^T ----------------
// grid 256 (b=bid&7 XCD-pinned), 512 threads = 8 waves (2 row-grp x 4 col-grp).
// BM=64, BN=320. A = packed bits in LDS. B loaded via VOLATILE-ASM
// global_load_dwordx4 into 15 NAMED uint4 registers (3 sets x 5) — asm-defined
// values cannot be sunk/rematerialized by the compiler (R16: C-level loads were
// rotated to depth-0, VGPR=92). Counted s_waitcnt vmcnt(10) + sched_barrier(0)
// gates (rule #18). Steady state: 2 sets (10 loads) always in flight.
__global__ __launch_bounds__(512, 1) void gat_main(
    const unsigned* __restrict__ pk, const unsigned short* __restrict__ Bt,
    float* __restrict__ out) {
  __shared__ __align__(16) char lds[64 * 272 + 256];  // A bits (stride 272) + den
  const int bid = blockIdx.x;
  const int b   = bid & 7;
  const int rb  = bid >> 3;
  const int i0  = rb * 64;
  const int tid = threadIdx.x;
  const int w   = tid >> 6, L = tid & 63;
  const int wm  = w >> 2, wn = w & 3;     // row-group, col-group
  const int fr  = L & 15, kc = L >> 4;

  // prologue: stage 64 rows x 256B of packed bits, row stride 272 (coalesced)
  {
    int r = tid >> 3, seg = tid & 7;
    const char* src = (const char*)pk + ((size_t)(b * 2048 + i0 + r) * 256 + seg * 32);
    char* dst = lds + r * 272 + seg * 32;
    *(int4*)(dst)      = *(const int4*)(src);
    *(int4*)(dst + 16) = *(const int4*)(src + 16);
  }
  __syncthreads();

  const char* bsrc = (const char*)Bt + (size_t)b * 1310720
                   + (size_t)(wn * 80 + fr) * 64 + (kc << 4);
  const char* arow0 = lds + (wm * 32 + fr) * 272;
  const char* arow1 = arow0 + 16 * 272;
  const int   ksh   = kc * 8;

  floatx4 acc[2][5];
#pragma unroll
  for (int i = 0; i < 2; ++i)
#pragma unroll
    for (int n = 0; n < 5; ++n) acc[i][n] = (floatx4)0.0f;

  // 15 named asm-defined registers: 3 sets x 5 fragments
  uint4v s0_0, s0_1, s0_2, s0_3, s0_4;
  uint4v s1_0, s1_1, s1_2, s1_3, s1_4;
  uint4v s2_0, s2_1, s2_2, s2_3, s2_4;

#define GL(DST, P, OFF) \
  asm volatile("global_load_dwordx4 %0, %1, off offset:" #OFF \
               : "=v"(DST) : "v"(P))

#define LOADB(TT, SET) {                                  \
    const char* p_ = bsrc + (size_t)(TT) * 20480;         \
    const char* q_ = p_ + 4096;                           \
    GL(SET##_0, p_, 0);                                   \
    GL(SET##_1, p_, 1024);                                \
    GL(SET##_2, p_, 2048);                                \
    GL(SET##_3, p_, 3072);                                \
    GL(SET##_4, q_, 0);                                   \
  }

#define GATE(N) {                                         \
    asm volatile("s_waitcnt vmcnt(" #N ")");              \
    __builtin_amdgcn_sched_barrier(0);                    \
  }

  // bit->bf16 expand: y = x | x<<15; dword j = ((y>>2j) & 0x10001) * 0x3F80
#define AFRAG(WORD, DST) {                                \
    unsigned x_ = ((WORD) >> ksh) & 0xFFu;                \
    unsigned y_ = x_ | (x_ << 15);                        \
    union { unsigned u[4]; short8 s; } c_;                \
    c_.u[0] = (y_        & 0x10001u) * 0x3F80u;           \
    c_.u[1] = ((y_ >> 2) & 0x10001u) * 0x3F80u;           \
    c_.u[2] = ((y_ >> 4) & 0x10001u) * 0x3F80u;           \
    c_.u[3] = ((y_ >> 6) & 0x10001u) * 0x3F80u;           \
    DST = c_.s;                                           \
  }

#define COMPUTE(TT, SET) {                                                       \
    unsigned aw0_ = *(const unsigned*)(arow0 + (TT) * 4);                        \
    unsigned aw1_ = *(const unsigned*)(arow1 + (TT) * 4);                        \
    short8 af0_, af1_;                                                           \
    AFRAG(aw0_, af0_);                                                           \
    AFRAG(aw1_, af1_);                                                           \
    short8 b0_ = bc8(SET##_0), b1_ = bc8(SET##_1), b2_ = bc8(SET##_2);           \
    short8 b3_ = bc8(SET##_3), b4_ = bc8(SET##_4);                               \
    acc[0][0] = __builtin_amdgcn_mfma_f32_16x16x32_bf16(af0_, b0_, acc[0][0], 0, 0, 0); \
    acc[1][0] = __builtin_amdgcn_mfma_f32_16x16x32_bf16(af1_, b0_, acc[1][0], 0, 0, 0); \
    acc[0][1] = __builtin_amdgcn_mfma_f32_16x16x32_bf16(af0_, b1_, acc[0][1], 0, 0, 0); \
    acc[1][1] = __builtin_amdgcn_mfma_f32_16x16x32_bf16(af1_, b1_, acc[1][1], 0, 0, 0); \
    acc[0][2] = __builtin_amdgcn_mfma_f32_16x16x32_bf16(af0_, b2_, acc[0][2], 0, 0, 0); \
    acc[1][2] = __builtin_amdgcn_mfma_f32_16x16x32_bf16(af1_, b2_, acc[1][2], 0, 0, 0); \
    acc[0][3] = __builtin_amdgcn_mfma_f32_16x16x32_bf16(af0_, b3_, acc[0][3], 0, 0, 0); \
    acc[1][3] = __builtin_amdgcn_mfma_f32_16x16x32_bf16(af1_, b3_, acc[1][3], 0, 0, 0); \
    acc[0][4] = __builtin_amdgcn_mfma_f32_16x16x32_bf16(af0_, b4_, acc[0][4], 0, 0, 0); \
    acc[1][4] = __builtin_amdgcn_mfma_f32_16x16x32_bf16(af1_, b4_, acc[1][4], 0, 0, 0); \
  }

  LOADB(0, s0); LOADB(1, s1); LOADB(2, s2);   // 15 outstanding

#pragma unroll 1
  for (int kt = 0; kt < 60; kt += 3) {
    GATE(10); COMPUTE(kt + 0, s0); LOADB(kt + 3, s0);
    GATE(10); COMPUTE(kt + 1, s1); LOADB(kt + 4, s1);
    GATE(10); COMPUTE(kt + 2, s2); LOADB(kt + 5, s2);
  }
  // after loop: tiles 60(s0), 61(s1), 62(s2) loaded; 15 outstanding
  GATE(10); COMPUTE(60, s0); LOADB(63, s0);   // -> 15 outstanding
  GATE(10); COMPUTE(61, s1);
  GATE(5);  COMPUTE(62, s2);
  GATE(0);  COMPUTE(63, s0);

  // epilogue: den = col 256 -> wn==3, nf==1, fr==0
  float* denL = (float*)(lds + 64 * 272);
  const int q = L >> 4;
  if (wn == 3 && fr == 0) {
#pragma unroll
    for (int mf = 0; mf < 2; ++mf)
#pragma unroll
      for (int jj = 0; jj < 4; ++jj)
        denL[wm * 32 + mf * 16 + q * 4 + jj] = acc[mf][1][jj];
  }
  __syncthreads();
  float invd[2][4];
#pragma unroll
  for (int mf = 0; mf < 2; ++mf)
#pragma unroll
    for (int jj = 0; jj < 4; ++jj)
      invd[mf][jj] = 1.0f / denL[wm * 32 + mf * 16 + q * 4 + jj];
#pragma unroll
  for (int mf = 0; mf < 2; ++mf) {
#pragma unroll
    for (int nf = 0; nf < 5; ++nf) {
      int col = wn * 80 + nf * 16 + fr;
      if (col < 256) {
#pragma unroll
        for (int jj = 0; jj < 4; ++jj) {
          int row = wm * 32 + mf * 16 + q * 4 + jj;
          float v = acc[mf][nf][jj] * invd[mf][jj];
          v = (v > 0.0f) ? v : expm1f(v);
          out[((size_t)b * 2048 + i0 + row) * 256 + col] = v;
        }
      }
    }
  }
#undef COMPUTE
#undef AFRAG
#undef GATE
#undef LOADB
#undef GL
}

extern "C" void kernel_launch(void* const* d_in, const int* in_sizes, int n_in,
                              void* d_out, int out_size, void* d_ws, size_t ws_size,
                              hipStream_t stream) {
  const float* h   = (const float*)d_in[0];
  const int*   adj = (const int*)d_in[1];
  const float* W   = (const float*)d_in[2];
  const float* a   = (const float*)d_in[3];
  float* out = (float*)d_out;

  char* ws = (char*)d_ws;
  if (ws_size < 23265536) return;
  unsigned short* Whb = (unsigned short*)ws;              //  8,388,608 B
  float* g            = (float*)(ws + 8388608);           //     65,536 B
  float* Mb           = (float*)(ws + 8454144);           //        256 B
  unsigned short* Bt  = (unsigned short*)(ws + 8454400);  // 10,485,760 B
  unsigned short* Wt  = (unsigned short*)(ws + 18940160); //    131,072 B
  unsigned* pk        = (unsigned*)(ws + 19071232);       //  4,194,304 B

  hipMemsetAsync(g, 0, 65536, stream);
  adj_pack <<<4096, 256, 0, stream>>>(adj, pk);
  wt_conv  <<<256,  256, 0, stream>>>(W, Wt);
  wh_mfma  <<<512,  256, 0, stream>>>(h, Wt, Whb, a, g);
  batch_max<<<8,    256, 0, stream>>>(g, Mb);
  build_bt <<<256,  256, 0, stream>>>(Whb, g, Mb, Bt);
  gat_main <<<256,  512, 0, stream>>>(pk, Bt, out);
}

// Round 18
// 88.053 us; speedup vs baseline: 1.2304x; 1.1755x over previous
//
#include <hip/hip_runtime.h>
#include <math.h>

using short8   = __attribute__((ext_vector_type(8))) short;
using floatx4  = __attribute__((ext_vector_type(4))) float;
using ushort4v = __attribute__((ext_vector_type(4))) unsigned short;
using uint4v   = __attribute__((ext_vector_type(4))) unsigned int;

__device__ __forceinline__ unsigned short f2bf(float x) {
  union { float f; unsigned u; } v; v.f = x;
  unsigned r = (v.u + 0x7FFFu + ((v.u >> 16) & 1u)) >> 16;
  return (unsigned short)r;
}
__device__ __forceinline__ float bf2f(unsigned short u) {
  union { unsigned u; float f; } v; v.u = ((unsigned)u) << 16;
  return v.f;
}
__device__ __forceinline__ short8 cvt8(const float* p) {
  float4 v0 = *(const float4*)p;
  float4 v1 = *(const float4*)(p + 4);
  short8 r;
  r[0] = (short)f2bf(v0.x); r[1] = (short)f2bf(v0.y);
  r[2] = (short)f2bf(v0.z); r[3] = (short)f2bf(v0.w);
  r[4] = (short)f2bf(v1.x); r[5] = (short)f2bf(v1.y);
  r[6] = (short)f2bf(v1.z); r[7] = (short)f2bf(v1.w);
  return r;
}
__device__ __forceinline__ short8 bc8(uint4v v) {
  union { uint4v u; short8 s; } x; x.u = v; return x.s;
}

// ---------------- K0a: pack adj int32 -> bit per element (coalesced) ----------------
__global__ __launch_bounds__(256) void adj_pack(
    const int* __restrict__ adj, unsigned* __restrict__ pk) {
  size_t tid = (size_t)blockIdx.x * 256 + threadIdx.x;   // 0..1,048,575
  const int* src = adj + tid * 32;
  unsigned r = 0;
#pragma unroll
  for (int q = 0; q < 8; ++q) {
    int4 v = *(const int4*)(src + q * 4);
    r |= ((unsigned)v.x << (4 * q)) | ((unsigned)v.y << (4 * q + 1)) |
         ((unsigned)v.z << (4 * q + 2)) | ((unsigned)v.w << (4 * q + 3));
  }
  pk[tid] = r;
}

// ---------------- K0b: W -> Wt, LANE-CONSECUTIVE fragment layout ----------------
// Group = (kt, nfg): 1KB holding 16 cols x 32 k. Lane L=(kc=L>>4, fr=L&15)'s
// 16B fragment (col nfg*16+fr, k-slot kc) sits at byte offset L*16.
__global__ __launch_bounds__(256) void wt_conv(
    const float* __restrict__ W, unsigned short* __restrict__ Wt) {
  int c = blockIdx.x;           // col
  int k = threadIdx.x;          // k index
  int kt = k >> 5, kc = (k >> 3) & 3, e = k & 7;
  size_t dst = (size_t)kt * 16384 + (size_t)(c >> 4) * 1024
             + (size_t)(kc * 16 + (c & 15)) * 16 + e * 2;
  *(unsigned short*)((char*)Wt + dst) = f2bf(W[(size_t)k * 256 + c]);
}

// ---------------- K1: Wh = h @ W via bf16 MFMA (f32 accum) + fused g-dot ----------------
__global__ __launch_bounds__(256) void wh_mfma(
    const float* __restrict__ h, const unsigned short* __restrict__ Wt,
    unsigned short* __restrict__ Whb, const float* __restrict__ a,
    float* __restrict__ g) {
  const int m0 = blockIdx.x * 32;
  const int t  = threadIdx.x;
  const int w  = t >> 6, L = t & 63;
  const int fr = L & 15, kc = L >> 4;

  const float* hrow0 = h + (size_t)(m0 + fr) * 256;
  const float* hrow1 = h + (size_t)(m0 + 16 + fr) * 256;
  const char*  WtB   = (const char*)Wt;

  floatx4 acc[2][4];
#pragma unroll
  for (int i = 0; i < 2; ++i)
#pragma unroll
    for (int n = 0; n < 4; ++n) acc[i][n] = (floatx4)0.0f;

#pragma unroll
  for (int kt = 0; kt < 8; ++kt) {
    short8 a0 = cvt8(hrow0 + kt * 32 + kc * 8);
    short8 a1 = cvt8(hrow1 + kt * 32 + kc * 8);
#pragma unroll
    for (int nf = 0; nf < 4; ++nf) {
      short8 bf = *(const short8*)(WtB + (size_t)kt * 16384
                                   + (size_t)(w * 4 + nf) * 1024 + (size_t)L * 16);
      acc[0][nf] = __builtin_amdgcn_mfma_f32_16x16x32_bf16(a0, bf, acc[0][nf], 0, 0, 0);
      acc[1][nf] = __builtin_amdgcn_mfma_f32_16x16x32_bf16(a1, bf, acc[1][nf], 0, 0, 0);
    }
  }

  const int q = L >> 4;
  float a2v[4];
#pragma unroll
  for (int nf = 0; nf < 4; ++nf) a2v[nf] = a[256 + w * 64 + nf * 16 + fr];
#pragma unroll
  for (int mf = 0; mf < 2; ++mf) {
    float p[4] = {0.f, 0.f, 0.f, 0.f};
#pragma unroll
    for (int nf = 0; nf < 4; ++nf) {
#pragma unroll
      for (int jj = 0; jj < 4; ++jj) {
        int row = m0 + mf * 16 + q * 4 + jj;
        Whb[(size_t)row * 256 + w * 64 + nf * 16 + fr] = f2bf(acc[mf][nf][jj]);
        p[jj] += acc[mf][nf][jj] * a2v[nf];
      }
    }
#pragma unroll
    for (int jj = 0; jj < 4; ++jj) {
#pragma unroll
      for (int off = 1; off < 16; off <<= 1) p[jj] += __shfl_xor(p[jj], off);
      if (fr == 0) atomicAdd(&g[m0 + mf * 16 + q * 4 + jj], p[jj]);
    }
  }
}

// ---------------- K2b: per-batch max of g ----------------
__global__ __launch_bounds__(256) void batch_max(
    const float* __restrict__ g, float* __restrict__ Mb) {
  __shared__ float red[4];
  int b = blockIdx.x, t = threadIdx.x;
  float m = -1e30f;
  for (int i = t; i < 2048; i += 256) m = fmaxf(m, g[(size_t)b * 2048 + i]);
#pragma unroll
  for (int off = 32; off > 0; off >>= 1) m = fmaxf(m, __shfl_xor(m, off));
  if ((t & 63) == 0) red[t >> 6] = m;
  __syncthreads();
  if (t == 0) Mb[b] = fmaxf(fmaxf(red[0], red[1]), fmaxf(red[2], red[3]));
}

// ---------------- K2c: Bt in LANE-CONSECUTIVE layout ----------------
// Bt[tile=(b*64+kt)] = 20KB: nfg (20 groups of 16 cols) x 1KB; within a group,
// lane L=(kc,fr)'s 16B (col nfg*16+fr, k-slot kc) at byte offset (kc*16+fr)*16.
__global__ __launch_bounds__(256) void build_bt(
    const unsigned short* __restrict__ Whb, const float* __restrict__ g,
    const float* __restrict__ Mb, unsigned short* __restrict__ Bt) {
  __shared__ __align__(16) unsigned short tile[320 * 72];
  const int blk = blockIdx.x;
  const int b   = blk >> 5;
  const int j0  = (blk & 31) * 64;
  const int kt_base = (blk & 31) * 2;
  const int t   = threadIdx.x;
  const int j   = t & 63;
  const int q0  = t >> 6;
  const int row = b * 2048 + j0 + j;
  const float s = expf(g[row] - Mb[b]);
  for (int q = q0; q < 64; q += 4) {
    ushort4v wv = *(const ushort4v*)&Whb[(size_t)row * 256 + q * 4];
    int c = q * 4;
    tile[(c + 0) * 72 + j] = f2bf(s * bf2f(wv[0]));
    tile[(c + 1) * 72 + j] = f2bf(s * bf2f(wv[1]));
    tile[(c + 2) * 72 + j] = f2bf(s * bf2f(wv[2]));
    tile[(c + 3) * 72 + j] = f2bf(s * bf2f(wv[3]));
  }
  if (q0 == 0) tile[256 * 72 + j] = f2bf(s);
  for (int z = t; z < 63 * 64; z += 256) {
    int c = 257 + (z >> 6);
    tile[c * 72 + (z & 63)] = 0;
  }
  __syncthreads();
  // scatter: id -> (kt_l, nfg, slot, fr); consecutive t => consecutive 16B dst
#pragma unroll
  for (int p = 0; p < 10; ++p) {
    int id   = t + 256 * p;          // 0..2559
    int fr   = id & 15;
    int slot = (id >> 4) & 3;
    int rest = id >> 6;              // 0..39
    int nfg  = rest % 20;
    int kt_l = rest / 20;
    const unsigned short* src = &tile[(nfg * 16 + fr) * 72 + kt_l * 32 + slot * 8];
    size_t dst = (size_t)(b * 64 + kt_base + kt_l) * 20480
               + (size_t)nfg * 1024 + (size_t)(slot * 16 + fr) * 16;
    *(int4*)((char*)Bt + dst) = *(const int4*)src;
  }
}

// ---------------- K3: [num|den] = adj @ Bt^T ----------------
// grid 256 (b=bid&7 XCD-pinned), 512 threads = 8 waves (2 row-grp x 4 col-grp).
// BM=64, BN=320. A = packed bits in LDS. B via volatile-asm dwordx4 into 15
// named regs (3 sets x 5), counted vmcnt gates. NEW: Bt layout is lane-
// consecutive (lane L reads byte L*16 of each 1KB group) -> the TA coalescer
// merges each load into full-line transactions instead of 64 x 16B requests
// (R15-R17 invariant: ~32 GB/s/CU = 77 cyc/instr = per-lane shatter).
__global__ __launch_bounds__(512, 1) void gat_main(
    const unsigned* __restrict__ pk, const unsigned short* __restrict__ Bt,
    float* __restrict__ out) {
  __shared__ __align__(16) char lds[64 * 272 + 256];  // A bits (stride 272) + den
  const int bid = blockIdx.x;
  const int b   = bid & 7;
  const int rb  = bid >> 3;
  const int i0  = rb * 64;
  const int tid = threadIdx.x;
  const int w   = tid >> 6, L = tid & 63;
  const int wm  = w >> 2, wn = w & 3;     // row-group, col-group
  const int fr  = L & 15, kc = L >> 4;

  // prologue: stage 64 rows x 256B of packed bits, row stride 272 (coalesced)
  {
    int r = tid >> 3, seg = tid & 7;
    const char* src = (const char*)pk + ((size_t)(b * 2048 + i0 + r) * 256 + seg * 32);
    char* dst = lds + r * 272 + seg * 32;
    *(int4*)(dst)      = *(const int4*)(src);
    *(int4*)(dst + 16) = *(const int4*)(src + 16);
  }
  __syncthreads();

  // lane-consecutive B source: group nfg = wn*5 + nf at +nf*1024, lane at +L*16
  const char* bsrc = (const char*)Bt + (size_t)b * 1310720
                   + (size_t)(wn * 5) * 1024 + (size_t)L * 16;
  const char* arow0 = lds + (wm * 32 + fr) * 272;
  const char* arow1 = arow0 + 16 * 272;
  const int   ksh   = kc * 8;

  floatx4 acc[2][5];
#pragma unroll
  for (int i = 0; i < 2; ++i)
#pragma unroll
    for (int n = 0; n < 5; ++n) acc[i][n] = (floatx4)0.0f;

  // 15 named asm-defined registers: 3 sets x 5 fragments
  uint4v s0_0, s0_1, s0_2, s0_3, s0_4;
  uint4v s1_0, s1_1, s1_2, s1_3, s1_4;
  uint4v s2_0, s2_1, s2_2, s2_3, s2_4;

#define GL(DST, P, OFF) \
  asm volatile("global_load_dwordx4 %0, %1, off offset:" #OFF \
               : "=v"(DST) : "v"(P))

#define LOADB(TT, SET) {                                  \
    const char* p_ = bsrc + (size_t)(TT) * 20480;         \
    const char* q_ = p_ + 4096;                           \
    GL(SET##_0, p_, 0);                                   \
    GL(SET##_1, p_, 1024);                                \
    GL(SET##_2, p_, 2048);                                \
    GL(SET##_3, p_, 3072);                                \
    GL(SET##_4, q_, 0);                                   \
  }

#define GATE(N) {                                         \
    asm volatile("s_waitcnt vmcnt(" #N ")");              \
    __builtin_amdgcn_sched_barrier(0);                    \
  }

  // bit->bf16 expand: y = x | x<<15; dword j = ((y>>2j) & 0x10001) * 0x3F80
#define AFRAG(WORD, DST) {                                \
    unsigned x_ = ((WORD) >> ksh) & 0xFFu;                \
    unsigned y_ = x_ | (x_ << 15);                        \
    union { unsigned u[4]; short8 s; } c_;                \
    c_.u[0] = (y_        & 0x10001u) * 0x3F80u;           \
    c_.u[1] = ((y_ >> 2) & 0x10001u) * 0x3F80u;           \
    c_.u[2] = ((y_ >> 4) & 0x10001u) * 0x3F80u;           \
    c_.u[3] = ((y_ >> 6) & 0x10001u) * 0x3F80u;           \
    DST = c_.s;                                           \
  }

#define COMPUTE(TT, SET) {                                                       \
    unsigned aw0_ = *(const unsigned*)(arow0 + (TT) * 4);                        \
    unsigned aw1_ = *(const unsigned*)(arow1 + (TT) * 4);                        \
    short8 af0_, af1_;                                                           \
    AFRAG(aw0_, af0_);                                                           \
    AFRAG(aw1_, af1_);                                                           \
    short8 b0_ = bc8(SET##_0), b1_ = bc8(SET##_1), b2_ = bc8(SET##_2);           \
    short8 b3_ = bc8(SET##_3), b4_ = bc8(SET##_4);                               \
    acc[0][0] = __builtin_amdgcn_mfma_f32_16x16x32_bf16(af0_, b0_, acc[0][0], 0, 0, 0); \
    acc[1][0] = __builtin_amdgcn_mfma_f32_16x16x32_bf16(af1_, b0_, acc[1][0], 0, 0, 0); \
    acc[0][1] = __builtin_amdgcn_mfma_f32_16x16x32_bf16(af0_, b1_, acc[0][1], 0, 0, 0); \
    acc[1][1] = __builtin_amdgcn_mfma_f32_16x16x32_bf16(af1_, b1_, acc[1][1], 0, 0, 0); \
    acc[0][2] = __builtin_amdgcn_mfma_f32_16x16x32_bf16(af0_, b2_, acc[0][2], 0, 0, 0); \
    acc[1][2] = __builtin_amdgcn_mfma_f32_16x16x32_bf16(af1_, b2_, acc[1][2], 0, 0, 0); \
    acc[0][3] = __builtin_amdgcn_mfma_f32_16x16x32_bf16(af0_, b3_, acc[0][3], 0, 0, 0); \
    acc[1][3] = __builtin_amdgcn_mfma_f32_16x16x32_bf16(af1_, b3_, acc[1][3], 0, 0, 0); \
    acc[0][4] = __builtin_amdgcn_mfma_f32_16x16x32_bf16(af0_, b4_, acc[0][4], 0, 0, 0); \
    acc[1][4] = __builtin_amdgcn_mfma_f32_16x16x32_bf16(af1_, b4_, acc[1][4], 0, 0, 0); \
  }

  LOADB(0, s0); LOADB(1, s1); LOADB(2, s2);   // 15 outstanding

#pragma unroll 1
  for (int kt = 0; kt < 60; kt += 3) {
    GATE(10); COMPUTE(kt + 0, s0); LOADB(kt + 3, s0);
    GATE(10); COMPUTE(kt + 1, s1); LOADB(kt + 4, s1);
    GATE(10); COMPUTE(kt + 2, s2); LOADB(kt + 5, s2);
  }
  GATE(10); COMPUTE(60, s0); LOADB(63, s0);
  GATE(10); COMPUTE(61, s1);
  GATE(5);  COMPUTE(62, s2);
  GATE(0);  COMPUTE(63, s0);

  // epilogue: den = col 256 -> wn==3, nf==1, fr==0
  float* denL = (float*)(lds + 64 * 272);
  const int q = L >> 4;
  if (wn == 3 && fr == 0) {
#pragma unroll
    for (int mf = 0; mf < 2; ++mf)
#pragma unroll
      for (int jj = 0; jj < 4; ++jj)
        denL[wm * 32 + mf * 16 + q * 4 + jj] = acc[mf][1][jj];
  }
  __syncthreads();
  float invd[2][4];
#pragma unroll
  for (int mf = 0; mf < 2; ++mf)
#pragma unroll
    for (int jj = 0; jj < 4; ++jj)
      invd[mf][jj] = 1.0f / denL[wm * 32 + mf * 16 + q * 4 + jj];
#pragma unroll
  for (int mf = 0; mf < 2; ++mf) {
#pragma unroll
    for (int nf = 0; nf < 5; ++nf) {
      int col = wn * 80 + nf * 16 + fr;
      if (col < 256) {
#pragma unroll
        for (int jj = 0; jj < 4; ++jj) {
          int row = wm * 32 + mf * 16 + q * 4 + jj;
          float v = acc[mf][nf][jj] * invd[mf][jj];
          v = (v > 0.0f) ? v : expm1f(v);
          out[((size_t)b * 2048 + i0 + row) * 256 + col] = v;
        }
      }
    }
  }
#undef COMPUTE
#undef AFRAG
#undef GATE
#undef LOADB
#undef GL
}

extern "C" void kernel_launch(void* const* d_in, const int* in_sizes, int n_in,
                              void* d_out, int out_size, void* d_ws, size_t ws_size,
                              hipStream_t stream) {
  const float* h   = (const float*)d_in[0];
  const int*   adj = (const int*)d_in[1];
  const float* W   = (const float*)d_in[2];
  const float* a   = (const float*)d_in[3];
  float* out = (float*)d_out;

  char* ws = (char*)d_ws;
  if (ws_size < 23265536) return;
  unsigned short* Whb = (unsigned short*)ws;              //  8,388,608 B
  float* g            = (float*)(ws + 8388608);           //     65,536 B
  float* Mb           = (float*)(ws + 8454144);           //        256 B
  unsigned short* Bt  = (unsigned short*)(ws + 8454400);  // 10,485,760 B
  unsigned short* Wt  = (unsigned short*)(ws + 18940160); //    131,072 B
  unsigned* pk        = (unsigned*)(ws + 19071232);       //  4,194,304 B

  hipMemsetAsync(g, 0, 65536, stream);
  adj_pack <<<4096, 256, 0, stream>>>(adj, pk);
  wt_conv  <<<256,  256, 0, stream>>>(W, Wt);
  wh_mfma  <<<512,  256, 0, stream>>>(h, Wt, Whb, a, g);
  batch_max<<<8,    256, 0, stream>>>(g, Mb);
  build_bt <<<256,  256, 0, stream>>>(Whb, g, Mb, Bt);
  gat_main <<<256,  512, 0, stream>>>(pk, Bt, out);
}